// Round 1
// baseline (1536.369 us; speedup 1.0000x reference)
//
#include <hip/hip_runtime.h>

// GCN decoder: z2 = A( relu(A(x)@W1 + b1) )@W2 + b2   with A = D^-1/2 (Adj+I) D^-1/2
// Aggregation done at width-128 in both layers (algebraic reordering).

constexpr int F = 128;    // aggregation width (n_latent = n_dim = 128)
constexpr int HID = 256;  // hidden width

__global__ __launch_bounds__(256) void k_init_deg(float* deg, int N) {
  int i = blockIdx.x * 256 + threadIdx.x;
  if (i < N) deg[i] = 1.0f;  // self-loop contributes 1
}

__global__ __launch_bounds__(256) void k_deg_edges(const int* __restrict__ dst,
                                                   float* deg, int E) {
  int e = blockIdx.x * 256 + threadIdx.x;
  if (e < E) atomicAdd(&deg[dst[e]], 1.0f);
}

__global__ __launch_bounds__(256) void k_dinv(float* deg, int N) {
  int i = blockIdx.x * 256 + threadIdx.x;
  if (i < N) deg[i] = rsqrtf(deg[i]);  // deg >= 1 always (self-loop)
}

// agg[i] = dinv[i]^2 * x[i]   (self-loop term, also zero-initializes)
__global__ __launch_bounds__(256) void k_agg_init(const float* __restrict__ x,
                                                  const float* __restrict__ dinv,
                                                  float* __restrict__ agg, int N) {
  int t = blockIdx.x * 256 + threadIdx.x;
  int i = t >> 5, f4 = t & 31;  // 32 float4 per row
  if (i >= N) return;
  float di = dinv[i];
  float w = di * di;
  float4 v = ((const float4*)(x + (size_t)i * F))[f4];
  v.x *= w; v.y *= w; v.z *= w; v.w *= w;
  ((float4*)(agg + (size_t)i * F))[f4] = v;
}

// agg[i] = bias + dinv[i]^2 * h[i]   (layer-2 init straight into d_out)
__global__ __launch_bounds__(256) void k_agg_init_bias(const float* __restrict__ h,
                                                       const float* __restrict__ dinv,
                                                       const float* __restrict__ bias,
                                                       float* __restrict__ agg, int N) {
  int t = blockIdx.x * 256 + threadIdx.x;
  int i = t >> 5, f4 = t & 31;
  if (i >= N) return;
  float di = dinv[i];
  float w = di * di;
  float4 v = ((const float4*)(h + (size_t)i * F))[f4];
  float4 bb = ((const float4*)bias)[f4];
  v.x = v.x * w + bb.x;
  v.y = v.y * w + bb.y;
  v.z = v.z * w + bb.z;
  v.w = v.w * w + bb.w;
  ((float4*)(agg + (size_t)i * F))[f4] = v;
}

// one wave (64 lanes) per edge; float2 per lane; 2 scalar f32 atomics per lane
__global__ __launch_bounds__(256) void k_agg_edges(const int* __restrict__ src,
                                                   const int* __restrict__ dst,
                                                   const float* __restrict__ dinv,
                                                   const float* __restrict__ h,
                                                   float* __restrict__ agg, int E) {
  int gid = blockIdx.x * 256 + threadIdx.x;
  int e = gid >> 6, lane = gid & 63;
  if (e >= E) return;
  int s = src[e], d = dst[e];
  float w = dinv[s] * dinv[d];
  float2 v = ((const float2*)(h + (size_t)s * F))[lane];
  float* out = agg + (size_t)d * F + lane * 2;
  atomicAdd(out, v.x * w);
  atomicAdd(out + 1, v.y * w);
}

// fp32 tiled GEMM: C[M,Nc] = A[M,K] @ B[K,Nc] (+bias) (optional relu)
// 64x64 tile, BK=64, 256 threads, 4x4 outputs/thread. K % 64 == 0, Nc % 64 == 0.
template <int BK>
__global__ __launch_bounds__(256) void k_gemm(const float* __restrict__ A,
                                              const float* __restrict__ B,
                                              const float* __restrict__ bias,
                                              float* __restrict__ C,
                                              int M, int K, int Nc, int do_relu) {
  __shared__ float As[64][BK + 1];
  __shared__ float Bs[BK][64 + 1];
  int tid = threadIdx.x;
  int tx = tid & 15, ty = tid >> 4;
  int row0 = blockIdx.x * 64;
  int col0 = blockIdx.y * 64;
  float acc[4][4] = {};

  for (int k0 = 0; k0 < K; k0 += BK) {
    constexpr int A_V = (64 * BK / 4) / 256;
#pragma unroll
    for (int l = 0; l < A_V; ++l) {
      int idx = l * 256 + tid;
      int r = idx / (BK / 4);
      int cv = idx % (BK / 4);
      float4 v = (row0 + r < M)
                     ? ((const float4*)(A + (size_t)(row0 + r) * K + k0))[cv]
                     : make_float4(0.f, 0.f, 0.f, 0.f);
      As[r][cv * 4 + 0] = v.x;
      As[r][cv * 4 + 1] = v.y;
      As[r][cv * 4 + 2] = v.z;
      As[r][cv * 4 + 3] = v.w;
    }
    constexpr int B_V = (BK * 64 / 4) / 256;
#pragma unroll
    for (int l = 0; l < B_V; ++l) {
      int idx = l * 256 + tid;
      int r = idx / 16;
      int cv = idx % 16;
      float4 v = ((const float4*)(B + (size_t)(k0 + r) * Nc + col0))[cv];
      Bs[r][cv * 4 + 0] = v.x;
      Bs[r][cv * 4 + 1] = v.y;
      Bs[r][cv * 4 + 2] = v.z;
      Bs[r][cv * 4 + 3] = v.w;
    }
    __syncthreads();
#pragma unroll
    for (int kk = 0; kk < BK; ++kk) {
      float a0 = As[ty * 4 + 0][kk];
      float a1 = As[ty * 4 + 1][kk];
      float a2 = As[ty * 4 + 2][kk];
      float a3 = As[ty * 4 + 3][kk];
      float b0 = Bs[kk][tx * 4 + 0];
      float b1v = Bs[kk][tx * 4 + 1];
      float b2v = Bs[kk][tx * 4 + 2];
      float b3 = Bs[kk][tx * 4 + 3];
      acc[0][0] += a0 * b0; acc[0][1] += a0 * b1v; acc[0][2] += a0 * b2v; acc[0][3] += a0 * b3;
      acc[1][0] += a1 * b0; acc[1][1] += a1 * b1v; acc[1][2] += a1 * b2v; acc[1][3] += a1 * b3;
      acc[2][0] += a2 * b0; acc[2][1] += a2 * b1v; acc[2][2] += a2 * b2v; acc[2][3] += a2 * b3;
      acc[3][0] += a3 * b0; acc[3][1] += a3 * b1v; acc[3][2] += a3 * b2v; acc[3][3] += a3 * b3;
    }
    __syncthreads();
  }

#pragma unroll
  for (int i = 0; i < 4; ++i) {
    int r = row0 + ty * 4 + i;
    if (r >= M) continue;
#pragma unroll
    for (int j = 0; j < 4; ++j) {
      int c = col0 + tx * 4 + j;
      float v = acc[i][j];
      if (bias) v += bias[c];
      if (do_relu) v = fmaxf(v, 0.f);
      C[(size_t)r * Nc + c] = v;
    }
  }
}

extern "C" void kernel_launch(void* const* d_in, const int* in_sizes, int n_in,
                              void* d_out, int out_size, void* d_ws, size_t ws_size,
                              hipStream_t stream) {
  const float* x = (const float*)d_in[0];
  const int* ei = (const int*)d_in[1];
  const float* W1 = (const float*)d_in[2];
  const float* b1 = (const float*)d_in[3];
  const float* W2 = (const float*)d_in[4];
  const float* b2 = (const float*)d_in[5];
  float* out = (float*)d_out;

  int N = in_sizes[0] / F;  // 50000
  int E = in_sizes[1] / 2;  // 800000
  const int* src = ei;
  const int* dst = ei + E;

  float* ws = (float*)d_ws;
  float* dinv = ws;                              // N floats (reused deg->dinv)
  float* agg1 = ws + (((size_t)N + 255) & ~(size_t)255);  // N*F
  float* z1 = agg1 + (size_t)N * F;              // N*HID
  float* h2 = z1 + (size_t)N * HID;              // N*F

  int nbN = (N + 255) / 256;
  k_init_deg<<<nbN, 256, 0, stream>>>(dinv, N);
  k_deg_edges<<<(E + 255) / 256, 256, 0, stream>>>(dst, dinv, E);
  k_dinv<<<nbN, 256, 0, stream>>>(dinv, N);

  int nbF = (int)(((size_t)N * 32 + 255) / 256);
  int nbE = (int)(((size_t)E * 64 + 255) / 256);

  // layer 1: agg1 = A x ; z1 = relu(agg1 @ W1 + b1)
  k_agg_init<<<nbF, 256, 0, stream>>>(x, dinv, agg1, N);
  k_agg_edges<<<nbE, 256, 0, stream>>>(src, dst, dinv, x, agg1, E);
  dim3 g1((N + 63) / 64, HID / 64);
  k_gemm<64><<<g1, 256, 0, stream>>>(agg1, W1, b1, z1, N, F, HID, 1);

  // layer 2: h2 = z1 @ W2 ; out = b2 + A h2
  dim3 g2((N + 63) / 64, F / 64);
  k_gemm<64><<<g2, 256, 0, stream>>>(z1, W2, nullptr, h2, N, HID, F, 0);
  k_agg_init_bias<<<nbF, 256, 0, stream>>>(h2, dinv, b2, out, N);
  k_agg_edges<<<nbE, 256, 0, stream>>>(src, dst, dinv, h2, out, E);
}

// Round 2
// 505.338 us; speedup vs baseline: 3.0403x; 3.0403x over previous
//
#include <hip/hip_runtime.h>

// GCN decoder: z2 = A( relu(A(x)@W1 + b1) )@W2 + b2,  A = D^-1/2 (Adj+I) D^-1/2
// Aggregation at width-128 both layers (algebraic reordering), CSR gather (no float atomics).

constexpr int F = 128;    // aggregation width
constexpr int HID = 256;  // hidden width

__global__ __launch_bounds__(256) void k_zero_deg(unsigned* deg, int N) {
  int i = blockIdx.x * 256 + threadIdx.x;
  if (i < N) deg[i] = 0u;
}

__global__ __launch_bounds__(256) void k_deg_hist(const int* __restrict__ dst,
                                                  unsigned* deg, int E) {
  int e = blockIdx.x * 256 + threadIdx.x;
  if (e < E) atomicAdd(&deg[dst[e]], 1u);
}

__global__ __launch_bounds__(256) void k_dinv(const unsigned* __restrict__ deg,
                                              float* dinv, int N) {
  int i = blockIdx.x * 256 + threadIdx.x;
  if (i < N) dinv[i] = rsqrtf((float)deg[i] + 1.0f);  // +1 = self-loop
}

// Single-block exclusive scan of deg -> rowptr; zeroes deg (becomes cursor).
__global__ __launch_bounds__(256) void k_scan(unsigned* __restrict__ deg,
                                              int* __restrict__ rowptr, int N) {
  __shared__ unsigned wsum[4];
  __shared__ unsigned carry;
  if (threadIdx.x == 0) carry = 0u;
  __syncthreads();
  int nchunk = (N + 255) / 256;
  for (int c = 0; c < nchunk; ++c) {
    int i = c * 256 + threadIdx.x;
    unsigned v = (i < N) ? deg[i] : 0u;
    unsigned sv = v;
#pragma unroll
    for (int off = 1; off < 64; off <<= 1) {
      unsigned t = __shfl_up(sv, off);
      if ((int)(threadIdx.x & 63) >= off) sv += t;
    }
    int w = threadIdx.x >> 6;
    if ((threadIdx.x & 63) == 63) wsum[w] = sv;
    __syncthreads();
    unsigned wpre = 0;
    for (int k = 0; k < w; ++k) wpre += wsum[k];
    unsigned excl = carry + wpre + sv - v;
    if (i < N) {
      rowptr[i] = (int)excl;
      deg[i] = 0u;  // reused as scatter cursor
    }
    __syncthreads();
    if (threadIdx.x == 255) carry = excl + v;  // chunk-inclusive total
    __syncthreads();
  }
  if (threadIdx.x == 0) rowptr[N] = (int)carry;
}

// Bucket edges by dst: esrc[pos]=src, ew[pos]=dinv[src]*dinv[dst]
__global__ __launch_bounds__(256) void k_scatter(const int* __restrict__ src,
                                                 const int* __restrict__ dst,
                                                 const int* __restrict__ rowptr,
                                                 unsigned* __restrict__ cursor,
                                                 const float* __restrict__ dinv,
                                                 int* __restrict__ esrc,
                                                 float* __restrict__ ew, int E) {
  int e = blockIdx.x * 256 + threadIdx.x;
  if (e >= E) return;
  int s = src[e], d = dst[e];
  unsigned pos = (unsigned)rowptr[d] + atomicAdd(&cursor[d], 1u);
  esrc[pos] = s;
  ew[pos] = dinv[s] * dinv[d];
}

// One wave per node: acc = (bias) + dinv[i]^2*h[i] + sum_e w_e * h[src_e]
template <int BIAS>
__global__ __launch_bounds__(256) void k_agg(const int* __restrict__ rowptr,
                                             const int* __restrict__ esrc,
                                             const float* __restrict__ ew,
                                             const float* __restrict__ dinv,
                                             const float* __restrict__ h,
                                             const float* __restrict__ bias,
                                             float* __restrict__ outp, int N) {
  int node = blockIdx.x * 4 + (threadIdx.x >> 6);
  int lane = threadIdx.x & 63;
  if (node >= N) return;
  float di = dinv[node];
  float w0 = di * di;
  float2 acc = ((const float2*)(h + (size_t)node * F))[lane];
  acc.x *= w0; acc.y *= w0;
  if (BIAS) {
    float2 bb = ((const float2*)bias)[lane];
    acc.x += bb.x; acc.y += bb.y;
  }
  int beg = rowptr[node], end = rowptr[node + 1];
  for (int b = beg; b < end; b += 64) {
    int n = min(64, end - b);
    int s = 0;
    float w = 0.f;
    if (lane < n) {
      s = esrc[b + lane];
      w = ew[b + lane];
    }
    int t = 0;
    for (; t + 1 < n; t += 2) {
      int s0 = __shfl(s, t), s1 = __shfl(s, t + 1);
      float wa = __shfl(w, t), wb = __shfl(w, t + 1);
      float2 v0 = ((const float2*)(h + (size_t)s0 * F))[lane];
      float2 v1 = ((const float2*)(h + (size_t)s1 * F))[lane];
      acc.x += v0.x * wa; acc.y += v0.y * wa;
      acc.x += v1.x * wb; acc.y += v1.y * wb;
    }
    if (t < n) {
      int s0 = __shfl(s, t);
      float wa = __shfl(w, t);
      float2 v0 = ((const float2*)(h + (size_t)s0 * F))[lane];
      acc.x += v0.x * wa; acc.y += v0.y * wa;
    }
  }
  ((float2*)(outp + (size_t)node * F))[lane] = acc;
}

// fp32 tiled GEMM: C[M,Nc] = A[M,K] @ B[K,Nc] (+bias) (optional relu)
template <int BK>
__global__ __launch_bounds__(256) void k_gemm(const float* __restrict__ A,
                                              const float* __restrict__ B,
                                              const float* __restrict__ bias,
                                              float* __restrict__ C,
                                              int M, int K, int Nc, int do_relu) {
  __shared__ float As[64][BK + 1];
  __shared__ float Bs[BK][64 + 1];
  int tid = threadIdx.x;
  int tx = tid & 15, ty = tid >> 4;
  int row0 = blockIdx.x * 64;
  int col0 = blockIdx.y * 64;
  float acc[4][4] = {};

  for (int k0 = 0; k0 < K; k0 += BK) {
    constexpr int A_V = (64 * BK / 4) / 256;
#pragma unroll
    for (int l = 0; l < A_V; ++l) {
      int idx = l * 256 + tid;
      int r = idx / (BK / 4);
      int cv = idx % (BK / 4);
      float4 v = (row0 + r < M)
                     ? ((const float4*)(A + (size_t)(row0 + r) * K + k0))[cv]
                     : make_float4(0.f, 0.f, 0.f, 0.f);
      As[r][cv * 4 + 0] = v.x;
      As[r][cv * 4 + 1] = v.y;
      As[r][cv * 4 + 2] = v.z;
      As[r][cv * 4 + 3] = v.w;
    }
    constexpr int B_V = (BK * 64 / 4) / 256;
#pragma unroll
    for (int l = 0; l < B_V; ++l) {
      int idx = l * 256 + tid;
      int r = idx / 16;
      int cv = idx % 16;
      float4 v = ((const float4*)(B + (size_t)(k0 + r) * Nc + col0))[cv];
      Bs[r][cv * 4 + 0] = v.x;
      Bs[r][cv * 4 + 1] = v.y;
      Bs[r][cv * 4 + 2] = v.z;
      Bs[r][cv * 4 + 3] = v.w;
    }
    __syncthreads();
#pragma unroll
    for (int kk = 0; kk < BK; ++kk) {
      float a0 = As[ty * 4 + 0][kk];
      float a1 = As[ty * 4 + 1][kk];
      float a2 = As[ty * 4 + 2][kk];
      float a3 = As[ty * 4 + 3][kk];
      float b0 = Bs[kk][tx * 4 + 0];
      float b1v = Bs[kk][tx * 4 + 1];
      float b2v = Bs[kk][tx * 4 + 2];
      float b3 = Bs[kk][tx * 4 + 3];
      acc[0][0] += a0 * b0; acc[0][1] += a0 * b1v; acc[0][2] += a0 * b2v; acc[0][3] += a0 * b3;
      acc[1][0] += a1 * b0; acc[1][1] += a1 * b1v; acc[1][2] += a1 * b2v; acc[1][3] += a1 * b3;
      acc[2][0] += a2 * b0; acc[2][1] += a2 * b1v; acc[2][2] += a2 * b2v; acc[2][3] += a2 * b3;
      acc[3][0] += a3 * b0; acc[3][1] += a3 * b1v; acc[3][2] += a3 * b2v; acc[3][3] += a3 * b3;
    }
    __syncthreads();
  }

#pragma unroll
  for (int i = 0; i < 4; ++i) {
    int r = row0 + ty * 4 + i;
    if (r >= M) continue;
#pragma unroll
    for (int j = 0; j < 4; ++j) {
      int c = col0 + tx * 4 + j;
      float v = acc[i][j];
      if (bias) v += bias[c];
      if (do_relu) v = fmaxf(v, 0.f);
      C[(size_t)r * Nc + c] = v;
    }
  }
}

extern "C" void kernel_launch(void* const* d_in, const int* in_sizes, int n_in,
                              void* d_out, int out_size, void* d_ws, size_t ws_size,
                              hipStream_t stream) {
  const float* x = (const float*)d_in[0];
  const int* ei = (const int*)d_in[1];
  const float* W1 = (const float*)d_in[2];
  const float* b1 = (const float*)d_in[3];
  const float* W2 = (const float*)d_in[4];
  const float* b2 = (const float*)d_in[5];
  float* out = (float*)d_out;

  int N = in_sizes[0] / F;  // 50000
  int E = in_sizes[1] / 2;  // 800000
  const int* src = ei;
  const int* dst = ei + E;

  // workspace layout (4-byte units)
  char* ws = (char*)d_ws;
  size_t off = 0;
  auto alloc = [&](size_t elems) {
    void* p = ws + off;
    off += ((elems * 4 + 255) & ~(size_t)255);
    return p;
  };
  unsigned* deg = (unsigned*)alloc(N);      // histogram, then scatter cursor
  float* dinv = (float*)alloc(N);
  int* rowptr = (int*)alloc(N + 1);
  int* esrc = (int*)alloc(E);
  float* ew = (float*)alloc(E);
  float* agg1 = (float*)alloc((size_t)N * F);   // reused as h2
  float* z1 = (float*)alloc((size_t)N * HID);
  float* h2 = agg1;

  int nbN = (N + 255) / 256;
  int nbE = (E + 255) / 256;
  k_zero_deg<<<nbN, 256, 0, stream>>>(deg, N);
  k_deg_hist<<<nbE, 256, 0, stream>>>(dst, deg, E);
  k_dinv<<<nbN, 256, 0, stream>>>(deg, dinv, N);
  k_scan<<<1, 256, 0, stream>>>(deg, rowptr, N);  // deg -> cursor (zeroed)
  k_scatter<<<nbE, 256, 0, stream>>>(src, dst, rowptr, deg, dinv, esrc, ew, E);

  int nbAgg = (N + 3) / 4;

  // layer 1: agg1 = A x ; z1 = relu(agg1 @ W1 + b1)
  k_agg<0><<<nbAgg, 256, 0, stream>>>(rowptr, esrc, ew, dinv, x, nullptr, agg1, N);
  dim3 g1((N + 63) / 64, HID / 64);
  k_gemm<64><<<g1, 256, 0, stream>>>(agg1, W1, b1, z1, N, F, HID, 1);

  // layer 2: h2 = z1 @ W2 ; out = b2 + A h2
  dim3 g2((N + 63) / 64, F / 64);
  k_gemm<64><<<g2, 256, 0, stream>>>(z1, W2, nullptr, h2, N, HID, F, 0);
  k_agg<1><<<nbAgg, 256, 0, stream>>>(rowptr, esrc, ew, dinv, h2, b2, out, N);
}

// Round 3
// 373.237 us; speedup vs baseline: 4.1163x; 1.3539x over previous
//
#include <hip/hip_runtime.h>

// GCN decoder: z2 = A( relu(A(x)@W1 + b1) )@W2 + b2,  A = D^-1/2 (Adj+I) D^-1/2
// Aggregation at width-128 both layers (algebraic reordering), CSR gather (no float atomics).
// Round 3: hierarchical 3-kernel prefix scan (was: 144us single-block scan).

constexpr int F = 128;    // aggregation width
constexpr int HID = 256;  // hidden width

__global__ __launch_bounds__(256) void k_zero_deg(unsigned* deg, int N) {
  int i = blockIdx.x * 256 + threadIdx.x;
  if (i < N) deg[i] = 0u;
}

__global__ __launch_bounds__(256) void k_deg_hist(const int* __restrict__ dst,
                                                  unsigned* deg, int E) {
  int e = blockIdx.x * 256 + threadIdx.x;
  if (e < E) atomicAdd(&deg[dst[e]], 1u);
}

__global__ __launch_bounds__(256) void k_dinv(const unsigned* __restrict__ deg,
                                              float* dinv, int N) {
  int i = blockIdx.x * 256 + threadIdx.x;
  if (i < N) dinv[i] = rsqrtf((float)deg[i] + 1.0f);  // +1 = self-loop
}

// scan stage 1: each block exclusive-scans its 256-elem chunk, emits chunk total
__global__ __launch_bounds__(256) void k_scan1(const unsigned* __restrict__ deg,
                                               int* __restrict__ rowptr,
                                               unsigned* __restrict__ bsum, int N) {
  __shared__ unsigned wsum[4];
  int i = blockIdx.x * 256 + threadIdx.x;
  unsigned v = (i < N) ? deg[i] : 0u;
  unsigned sv = v;
#pragma unroll
  for (int off = 1; off < 64; off <<= 1) {
    unsigned t = __shfl_up(sv, off);
    if ((int)(threadIdx.x & 63) >= off) sv += t;
  }
  int w = threadIdx.x >> 6;
  if ((threadIdx.x & 63) == 63) wsum[w] = sv;
  __syncthreads();
  unsigned wpre = 0;
  for (int k = 0; k < w; ++k) wpre += wsum[k];
  unsigned excl = wpre + sv - v;
  if (i < N) rowptr[i] = (int)excl;
  if (threadIdx.x == 255) bsum[blockIdx.x] = excl + v;
}

// scan stage 2: single block exclusive-scans the block sums in place; writes rowptr[N]
__global__ __launch_bounds__(256) void k_scan2(unsigned* __restrict__ bsum,
                                               int* __restrict__ rowptr, int nb, int N) {
  __shared__ unsigned wsum[4];
  __shared__ unsigned carry;
  if (threadIdx.x == 0) carry = 0u;
  __syncthreads();
  for (int c0 = 0; c0 < nb; c0 += 256) {
    int i = c0 + threadIdx.x;
    unsigned v = (i < nb) ? bsum[i] : 0u;
    unsigned sv = v;
#pragma unroll
    for (int off = 1; off < 64; off <<= 1) {
      unsigned t = __shfl_up(sv, off);
      if ((int)(threadIdx.x & 63) >= off) sv += t;
    }
    int w = threadIdx.x >> 6;
    if ((threadIdx.x & 63) == 63) wsum[w] = sv;
    __syncthreads();
    unsigned wpre = 0;
    for (int k = 0; k < w; ++k) wpre += wsum[k];
    unsigned excl = carry + wpre + sv - v;
    if (i < nb) bsum[i] = excl;
    __syncthreads();
    if (threadIdx.x == 255) carry = excl + v;
    __syncthreads();
  }
  if (threadIdx.x == 0) rowptr[N] = (int)carry;
}

// scan stage 3: add block offsets; zero the scatter cursor
__global__ __launch_bounds__(256) void k_scan3(const unsigned* __restrict__ bsum,
                                               int* __restrict__ rowptr,
                                               unsigned* __restrict__ cursor, int N) {
  int i = blockIdx.x * 256 + threadIdx.x;
  if (i < N) {
    rowptr[i] += (int)bsum[blockIdx.x];
    cursor[i] = 0u;
  }
}

// Bucket edges by dst: esrc[pos]=src, ew[pos]=dinv[src]*dinv[dst]
__global__ __launch_bounds__(256) void k_scatter(const int* __restrict__ src,
                                                 const int* __restrict__ dst,
                                                 const int* __restrict__ rowptr,
                                                 unsigned* __restrict__ cursor,
                                                 const float* __restrict__ dinv,
                                                 int* __restrict__ esrc,
                                                 float* __restrict__ ew, int E) {
  int e = blockIdx.x * 256 + threadIdx.x;
  if (e >= E) return;
  int s = src[e], d = dst[e];
  unsigned pos = (unsigned)rowptr[d] + atomicAdd(&cursor[d], 1u);
  esrc[pos] = s;
  ew[pos] = dinv[s] * dinv[d];
}

// One wave per node: acc = (bias) + dinv[i]^2*h[i] + sum_e w_e * h[src_e]
template <int BIAS>
__global__ __launch_bounds__(256) void k_agg(const int* __restrict__ rowptr,
                                             const int* __restrict__ esrc,
                                             const float* __restrict__ ew,
                                             const float* __restrict__ dinv,
                                             const float* __restrict__ h,
                                             const float* __restrict__ bias,
                                             float* __restrict__ outp, int N) {
  int node = blockIdx.x * 4 + (threadIdx.x >> 6);
  int lane = threadIdx.x & 63;
  if (node >= N) return;
  float di = dinv[node];
  float w0 = di * di;
  float2 acc = ((const float2*)(h + (size_t)node * F))[lane];
  acc.x *= w0; acc.y *= w0;
  if (BIAS) {
    float2 bb = ((const float2*)bias)[lane];
    acc.x += bb.x; acc.y += bb.y;
  }
  int beg = rowptr[node], end = rowptr[node + 1];
  for (int b = beg; b < end; b += 64) {
    int n = min(64, end - b);
    int s = 0;
    float w = 0.f;
    if (lane < n) {
      s = esrc[b + lane];
      w = ew[b + lane];
    }
    int t = 0;
    for (; t + 1 < n; t += 2) {
      int s0 = __shfl(s, t), s1 = __shfl(s, t + 1);
      float wa = __shfl(w, t), wb = __shfl(w, t + 1);
      float2 v0 = ((const float2*)(h + (size_t)s0 * F))[lane];
      float2 v1 = ((const float2*)(h + (size_t)s1 * F))[lane];
      acc.x += v0.x * wa; acc.y += v0.y * wa;
      acc.x += v1.x * wb; acc.y += v1.y * wb;
    }
    if (t < n) {
      int s0 = __shfl(s, t);
      float wa = __shfl(w, t);
      float2 v0 = ((const float2*)(h + (size_t)s0 * F))[lane];
      acc.x += v0.x * wa; acc.y += v0.y * wa;
    }
  }
  ((float2*)(outp + (size_t)node * F))[lane] = acc;
}

// fp32 tiled GEMM: C[M,Nc] = A[M,K] @ B[K,Nc] (+bias) (optional relu)
template <int BK>
__global__ __launch_bounds__(256) void k_gemm(const float* __restrict__ A,
                                              const float* __restrict__ B,
                                              const float* __restrict__ bias,
                                              float* __restrict__ C,
                                              int M, int K, int Nc, int do_relu) {
  __shared__ float As[64][BK + 1];
  __shared__ float Bs[BK][64 + 1];
  int tid = threadIdx.x;
  int tx = tid & 15, ty = tid >> 4;
  int row0 = blockIdx.x * 64;
  int col0 = blockIdx.y * 64;
  float acc[4][4] = {};

  for (int k0 = 0; k0 < K; k0 += BK) {
    constexpr int A_V = (64 * BK / 4) / 256;
#pragma unroll
    for (int l = 0; l < A_V; ++l) {
      int idx = l * 256 + tid;
      int r = idx / (BK / 4);
      int cv = idx % (BK / 4);
      float4 v = (row0 + r < M)
                     ? ((const float4*)(A + (size_t)(row0 + r) * K + k0))[cv]
                     : make_float4(0.f, 0.f, 0.f, 0.f);
      As[r][cv * 4 + 0] = v.x;
      As[r][cv * 4 + 1] = v.y;
      As[r][cv * 4 + 2] = v.z;
      As[r][cv * 4 + 3] = v.w;
    }
    constexpr int B_V = (BK * 64 / 4) / 256;
#pragma unroll
    for (int l = 0; l < B_V; ++l) {
      int idx = l * 256 + tid;
      int r = idx / 16;
      int cv = idx % 16;
      float4 v = ((const float4*)(B + (size_t)(k0 + r) * Nc + col0))[cv];
      Bs[r][cv * 4 + 0] = v.x;
      Bs[r][cv * 4 + 1] = v.y;
      Bs[r][cv * 4 + 2] = v.z;
      Bs[r][cv * 4 + 3] = v.w;
    }
    __syncthreads();
#pragma unroll
    for (int kk = 0; kk < BK; ++kk) {
      float a0 = As[ty * 4 + 0][kk];
      float a1 = As[ty * 4 + 1][kk];
      float a2 = As[ty * 4 + 2][kk];
      float a3 = As[ty * 4 + 3][kk];
      float b0 = Bs[kk][tx * 4 + 0];
      float b1v = Bs[kk][tx * 4 + 1];
      float b2v = Bs[kk][tx * 4 + 2];
      float b3 = Bs[kk][tx * 4 + 3];
      acc[0][0] += a0 * b0; acc[0][1] += a0 * b1v; acc[0][2] += a0 * b2v; acc[0][3] += a0 * b3;
      acc[1][0] += a1 * b0; acc[1][1] += a1 * b1v; acc[1][2] += a1 * b2v; acc[1][3] += a1 * b3;
      acc[2][0] += a2 * b0; acc[2][1] += a2 * b1v; acc[2][2] += a2 * b2v; acc[2][3] += a2 * b3;
      acc[3][0] += a3 * b0; acc[3][1] += a3 * b1v; acc[3][2] += a3 * b2v; acc[3][3] += a3 * b3;
    }
    __syncthreads();
  }

#pragma unroll
  for (int i = 0; i < 4; ++i) {
    int r = row0 + ty * 4 + i;
    if (r >= M) continue;
#pragma unroll
    for (int j = 0; j < 4; ++j) {
      int c = col0 + tx * 4 + j;
      float v = acc[i][j];
      if (bias) v += bias[c];
      if (do_relu) v = fmaxf(v, 0.f);
      C[(size_t)r * Nc + c] = v;
    }
  }
}

extern "C" void kernel_launch(void* const* d_in, const int* in_sizes, int n_in,
                              void* d_out, int out_size, void* d_ws, size_t ws_size,
                              hipStream_t stream) {
  const float* x = (const float*)d_in[0];
  const int* ei = (const int*)d_in[1];
  const float* W1 = (const float*)d_in[2];
  const float* b1 = (const float*)d_in[3];
  const float* W2 = (const float*)d_in[4];
  const float* b2 = (const float*)d_in[5];
  float* out = (float*)d_out;

  int N = in_sizes[0] / F;  // 50000
  int E = in_sizes[1] / 2;  // 800000
  const int* src = ei;
  const int* dst = ei + E;

  // workspace layout (4-byte units)
  char* ws = (char*)d_ws;
  size_t off = 0;
  auto alloc = [&](size_t elems) {
    void* p = ws + off;
    off += ((elems * 4 + 255) & ~(size_t)255);
    return p;
  };
  unsigned* deg = (unsigned*)alloc(N);      // histogram, then scatter cursor
  float* dinv = (float*)alloc(N);
  int* rowptr = (int*)alloc(N + 1);
  unsigned* bsum = (unsigned*)alloc(256);   // block sums for hierarchical scan
  int* esrc = (int*)alloc(E);
  float* ew = (float*)alloc(E);
  float* agg1 = (float*)alloc((size_t)N * F);   // reused as h2
  float* z1 = (float*)alloc((size_t)N * HID);
  float* h2 = agg1;

  int nbN = (N + 255) / 256;
  int nbE = (E + 255) / 256;
  k_zero_deg<<<nbN, 256, 0, stream>>>(deg, N);
  k_deg_hist<<<nbE, 256, 0, stream>>>(dst, deg, E);
  k_dinv<<<nbN, 256, 0, stream>>>(deg, dinv, N);
  k_scan1<<<nbN, 256, 0, stream>>>(deg, rowptr, bsum, N);
  k_scan2<<<1, 256, 0, stream>>>(bsum, rowptr, nbN, N);
  k_scan3<<<nbN, 256, 0, stream>>>(bsum, rowptr, deg, N);  // deg -> zeroed cursor
  k_scatter<<<nbE, 256, 0, stream>>>(src, dst, rowptr, deg, dinv, esrc, ew, E);

  int nbAgg = (N + 3) / 4;

  // layer 1: agg1 = A x ; z1 = relu(agg1 @ W1 + b1)
  k_agg<0><<<nbAgg, 256, 0, stream>>>(rowptr, esrc, ew, dinv, x, nullptr, agg1, N);
  dim3 g1((N + 63) / 64, HID / 64);
  k_gemm<64><<<g1, 256, 0, stream>>>(agg1, W1, b1, z1, N, F, HID, 1);

  // layer 2: h2 = z1 @ W2 ; out = b2 + A h2
  dim3 g2((N + 63) / 64, F / 64);
  k_gemm<64><<<g2, 256, 0, stream>>>(z1, W2, nullptr, h2, N, HID, F, 0);
  k_agg<1><<<nbAgg, 256, 0, stream>>>(rowptr, esrc, ew, dinv, h2, b2, out, N);
}

// Round 4
// 310.496 us; speedup vs baseline: 4.9481x; 1.2021x over previous
//
#include <hip/hip_runtime.h>

// GCN decoder: z2 = A( relu(A(x)@W1 + b1) )@W2 + b2,  A = D^-1/2 (Adj+I) D^-1/2
// Aggregation at width-128 both layers, CSR gather, hierarchical scan.
// Round 4: GEMMs via bf16 MFMA with 3-term split-bf16 (fp32-accurate to ~2^-18).

constexpr int F = 128;    // aggregation width
constexpr int HID = 256;  // hidden width

typedef __attribute__((ext_vector_type(8))) short bf16x8;
typedef __attribute__((ext_vector_type(4))) float f32x4;

__device__ inline unsigned short f2bf(float f) {
  unsigned u = __float_as_uint(f);
  u += 0x7fffu + ((u >> 16) & 1u);  // round-to-nearest-even
  return (unsigned short)(u >> 16);
}
__device__ inline float bf2f(unsigned short s) {
  return __uint_as_float(((unsigned)s) << 16);
}

__global__ __launch_bounds__(256) void k_zero_deg(unsigned* deg, int N) {
  int i = blockIdx.x * 256 + threadIdx.x;
  if (i < N) deg[i] = 0u;
}

__global__ __launch_bounds__(256) void k_deg_hist(const int* __restrict__ dst,
                                                  unsigned* deg, int E) {
  int e = blockIdx.x * 256 + threadIdx.x;
  if (e < E) atomicAdd(&deg[dst[e]], 1u);
}

__global__ __launch_bounds__(256) void k_dinv(const unsigned* __restrict__ deg,
                                              float* dinv, int N) {
  int i = blockIdx.x * 256 + threadIdx.x;
  if (i < N) dinv[i] = rsqrtf((float)deg[i] + 1.0f);  // +1 = self-loop
}

// transpose + split W[K][Nn] -> hi/lo [Nn][K] bf16
__global__ __launch_bounds__(256) void k_wsplit(const float* __restrict__ W,
                                                unsigned short* __restrict__ hi,
                                                unsigned short* __restrict__ lo,
                                                int K, int Nn) {
  int idx = blockIdx.x * 256 + threadIdx.x;
  if (idx >= K * Nn) return;
  int k = idx / Nn, n = idx - k * Nn;
  float f = W[idx];
  unsigned short h = f2bf(f);
  unsigned short l = f2bf(f - bf2f(h));
  hi[n * K + k] = h;
  lo[n * K + k] = l;
}

// scan stage 1: each block exclusive-scans its 256-elem chunk, emits chunk total
__global__ __launch_bounds__(256) void k_scan1(const unsigned* __restrict__ deg,
                                               int* __restrict__ rowptr,
                                               unsigned* __restrict__ bsum, int N) {
  __shared__ unsigned wsum[4];
  int i = blockIdx.x * 256 + threadIdx.x;
  unsigned v = (i < N) ? deg[i] : 0u;
  unsigned sv = v;
#pragma unroll
  for (int off = 1; off < 64; off <<= 1) {
    unsigned t = __shfl_up(sv, off);
    if ((int)(threadIdx.x & 63) >= off) sv += t;
  }
  int w = threadIdx.x >> 6;
  if ((threadIdx.x & 63) == 63) wsum[w] = sv;
  __syncthreads();
  unsigned wpre = 0;
  for (int k = 0; k < w; ++k) wpre += wsum[k];
  unsigned excl = wpre + sv - v;
  if (i < N) rowptr[i] = (int)excl;
  if (threadIdx.x == 255) bsum[blockIdx.x] = excl + v;
}

// scan stage 2: single block exclusive-scans block sums in place; writes rowptr[N]
__global__ __launch_bounds__(256) void k_scan2(unsigned* __restrict__ bsum,
                                               int* __restrict__ rowptr, int nb, int N) {
  __shared__ unsigned wsum[4];
  __shared__ unsigned carry;
  if (threadIdx.x == 0) carry = 0u;
  __syncthreads();
  for (int c0 = 0; c0 < nb; c0 += 256) {
    int i = c0 + threadIdx.x;
    unsigned v = (i < nb) ? bsum[i] : 0u;
    unsigned sv = v;
#pragma unroll
    for (int off = 1; off < 64; off <<= 1) {
      unsigned t = __shfl_up(sv, off);
      if ((int)(threadIdx.x & 63) >= off) sv += t;
    }
    int w = threadIdx.x >> 6;
    if ((threadIdx.x & 63) == 63) wsum[w] = sv;
    __syncthreads();
    unsigned wpre = 0;
    for (int k = 0; k < w; ++k) wpre += wsum[k];
    unsigned excl = carry + wpre + sv - v;
    if (i < nb) bsum[i] = excl;
    __syncthreads();
    if (threadIdx.x == 255) carry = excl + v;
    __syncthreads();
  }
  if (threadIdx.x == 0) rowptr[N] = (int)carry;
}

// scan stage 3: add block offsets; zero the scatter cursor
__global__ __launch_bounds__(256) void k_scan3(const unsigned* __restrict__ bsum,
                                               int* __restrict__ rowptr,
                                               unsigned* __restrict__ cursor, int N) {
  int i = blockIdx.x * 256 + threadIdx.x;
  if (i < N) {
    rowptr[i] += (int)bsum[blockIdx.x];
    cursor[i] = 0u;
  }
}

// Bucket edges by dst: esrc[pos]=src, ew[pos]=dinv[src]*dinv[dst]
__global__ __launch_bounds__(256) void k_scatter(const int* __restrict__ src,
                                                 const int* __restrict__ dst,
                                                 const int* __restrict__ rowptr,
                                                 unsigned* __restrict__ cursor,
                                                 const float* __restrict__ dinv,
                                                 int* __restrict__ esrc,
                                                 float* __restrict__ ew, int E) {
  int e = blockIdx.x * 256 + threadIdx.x;
  if (e >= E) return;
  int s = src[e], d = dst[e];
  unsigned pos = (unsigned)rowptr[d] + atomicAdd(&cursor[d], 1u);
  esrc[pos] = s;
  ew[pos] = dinv[s] * dinv[d];
}

// One wave per node: acc = (bias) + dinv[i]^2*h[i] + sum_e w_e * h[src_e]
template <int BIAS>
__global__ __launch_bounds__(256) void k_agg(const int* __restrict__ rowptr,
                                             const int* __restrict__ esrc,
                                             const float* __restrict__ ew,
                                             const float* __restrict__ dinv,
                                             const float* __restrict__ h,
                                             const float* __restrict__ bias,
                                             float* __restrict__ outp, int N) {
  int node = blockIdx.x * 4 + (threadIdx.x >> 6);
  int lane = threadIdx.x & 63;
  if (node >= N) return;
  float di = dinv[node];
  float w0 = di * di;
  float2 acc = ((const float2*)(h + (size_t)node * F))[lane];
  acc.x *= w0; acc.y *= w0;
  if (BIAS) {
    float2 bb = ((const float2*)bias)[lane];
    acc.x += bb.x; acc.y += bb.y;
  }
  int beg = rowptr[node], end = rowptr[node + 1];
  for (int b = beg; b < end; b += 64) {
    int n = min(64, end - b);
    int s = 0;
    float w = 0.f;
    if (lane < n) {
      s = esrc[b + lane];
      w = ew[b + lane];
    }
    int t = 0;
    for (; t + 1 < n; t += 2) {
      int s0 = __shfl(s, t), s1 = __shfl(s, t + 1);
      float wa = __shfl(w, t), wb = __shfl(w, t + 1);
      float2 v0 = ((const float2*)(h + (size_t)s0 * F))[lane];
      float2 v1 = ((const float2*)(h + (size_t)s1 * F))[lane];
      acc.x += v0.x * wa; acc.y += v0.y * wa;
      acc.x += v1.x * wb; acc.y += v1.y * wb;
    }
    if (t < n) {
      int s0 = __shfl(s, t);
      float wa = __shfl(w, t);
      float2 v0 = ((const float2*)(h + (size_t)s0 * F))[lane];
      acc.x += v0.x * wa; acc.y += v0.y * wa;
    }
  }
  ((float2*)(outp + (size_t)node * F))[lane] = acc;
}

// MFMA GEMM: C[M,Nc] = A[M,K](fp32) @ B (pre-split bf16, transposed [Nc][K]) (+bias)(+relu)
// 64x64 tile, BK=128, 4 waves of 32x32. Split-bf16 3-term: hh + h*lo + lo*h.
// LDS XOR-swizzle: ushort idx ^= (row&7)<<3  (16B granule) on both write & read.
__global__ __launch_bounds__(256) void k_mgemm(const float* __restrict__ A,
                                               const unsigned short* __restrict__ Bth,
                                               const unsigned short* __restrict__ Btl,
                                               const float* __restrict__ bias,
                                               float* __restrict__ C,
                                               int M, int K, int Nc, int do_relu) {
  __shared__ unsigned short Ah[64 * 128];  // 16 KB each
  __shared__ unsigned short Al[64 * 128];
  __shared__ unsigned short Bh[64 * 128];
  __shared__ unsigned short Bl[64 * 128];
  int tid = threadIdx.x;
  int lane = tid & 63, wid = tid >> 6;
  int wr = wid >> 1, wc = wid & 1;
  int row0 = blockIdx.x * 64, col0 = blockIdx.y * 64;

  f32x4 acc[2][2] = {};

  for (int k0 = 0; k0 < K; k0 += 128) {
    if (k0) __syncthreads();
    // stage A: 64 rows x 128 cols fp32 -> hi/lo bf16 (8 float4 per thread)
#pragma unroll
    for (int it = 0; it < 8; ++it) {
      int idx = it * 256 + tid;
      int r = idx >> 5, c4 = idx & 31;
      float4 v = make_float4(0.f, 0.f, 0.f, 0.f);
      if (row0 + r < M)
        v = *(const float4*)(A + (size_t)(row0 + r) * K + k0 + c4 * 4);
      ushort4 hv, lv;
      hv.x = f2bf(v.x); lv.x = f2bf(v.x - bf2f(hv.x));
      hv.y = f2bf(v.y); lv.y = f2bf(v.y - bf2f(hv.y));
      hv.z = f2bf(v.z); lv.z = f2bf(v.z - bf2f(hv.z));
      hv.w = f2bf(v.w); lv.w = f2bf(v.w - bf2f(hv.w));
      int o = r * 128 + ((c4 * 4) ^ ((r & 7) << 3));
      *(ushort4*)(Ah + o) = hv;
      *(ushort4*)(Al + o) = lv;
    }
    // stage B: 64 cols(rows of Bt) x 128 k bf16 hi+lo (4 x 16B per thread each)
#pragma unroll
    for (int it = 0; it < 4; ++it) {
      int idx = it * 256 + tid;
      int r = idx >> 4, c8 = idx & 15;
      size_t go = (size_t)(col0 + r) * K + k0 + c8 * 8;
      int o = r * 128 + ((c8 * 8) ^ ((r & 7) << 3));
      *(bf16x8*)(Bh + o) = *(const bf16x8*)(Bth + go);
      *(bf16x8*)(Bl + o) = *(const bf16x8*)(Btl + go);
    }
    __syncthreads();
#pragma unroll
    for (int ks = 0; ks < 4; ++ks) {
      int kb = ks * 32 + (lane >> 4) * 8;
      bf16x8 a_h[2], a_l[2], b_h[2], b_l[2];
#pragma unroll
      for (int mf = 0; mf < 2; ++mf) {
        int m = wr * 32 + mf * 16 + (lane & 15);
        int o = m * 128 + (kb ^ ((m & 7) << 3));
        a_h[mf] = *(const bf16x8*)(Ah + o);
        a_l[mf] = *(const bf16x8*)(Al + o);
      }
#pragma unroll
      for (int nf = 0; nf < 2; ++nf) {
        int n = wc * 32 + nf * 16 + (lane & 15);
        int o = n * 128 + (kb ^ ((n & 7) << 3));
        b_h[nf] = *(const bf16x8*)(Bh + o);
        b_l[nf] = *(const bf16x8*)(Bl + o);
      }
#pragma unroll
      for (int mf = 0; mf < 2; ++mf)
#pragma unroll
        for (int nf = 0; nf < 2; ++nf) {
          acc[mf][nf] = __builtin_amdgcn_mfma_f32_16x16x32_bf16(
              a_h[mf], b_h[nf], acc[mf][nf], 0, 0, 0);
          acc[mf][nf] = __builtin_amdgcn_mfma_f32_16x16x32_bf16(
              a_h[mf], b_l[nf], acc[mf][nf], 0, 0, 0);
          acc[mf][nf] = __builtin_amdgcn_mfma_f32_16x16x32_bf16(
              a_l[mf], b_h[nf], acc[mf][nf], 0, 0, 0);
        }
    }
  }
  // epilogue: D col=lane&15, row=(lane>>4)*4+reg
#pragma unroll
  for (int mf = 0; mf < 2; ++mf) {
    int r0 = row0 + wr * 32 + mf * 16 + (lane >> 4) * 4;
#pragma unroll
    for (int nf = 0; nf < 2; ++nf) {
      int c = col0 + wc * 32 + nf * 16 + (lane & 15);
      float bv = bias ? bias[c] : 0.f;
#pragma unroll
      for (int r = 0; r < 4; ++r) {
        if (r0 + r < M) {
          float v = acc[mf][nf][r] + bv;
          if (do_relu) v = fmaxf(v, 0.f);
          C[(size_t)(r0 + r) * Nc + c] = v;
        }
      }
    }
  }
}

extern "C" void kernel_launch(void* const* d_in, const int* in_sizes, int n_in,
                              void* d_out, int out_size, void* d_ws, size_t ws_size,
                              hipStream_t stream) {
  const float* x = (const float*)d_in[0];
  const int* ei = (const int*)d_in[1];
  const float* W1 = (const float*)d_in[2];
  const float* b1 = (const float*)d_in[3];
  const float* W2 = (const float*)d_in[4];
  const float* b2 = (const float*)d_in[5];
  float* out = (float*)d_out;

  int N = in_sizes[0] / F;  // 50000
  int E = in_sizes[1] / 2;  // 800000
  const int* src = ei;
  const int* dst = ei + E;

  // workspace layout (byte-based, 256B aligned chunks)
  char* ws = (char*)d_ws;
  size_t off = 0;
  auto allocB = [&](size_t bytes) {
    void* p = ws + off;
    off += ((bytes + 255) & ~(size_t)255);
    return p;
  };
  unsigned* deg = (unsigned*)allocB((size_t)N * 4);  // histogram, then cursor
  float* dinv = (float*)allocB((size_t)N * 4);
  int* rowptr = (int*)allocB(((size_t)N + 1) * 4);
  unsigned* bsum = (unsigned*)allocB(1024);
  int* esrc = (int*)allocB((size_t)E * 4);
  float* ew = (float*)allocB((size_t)E * 4);
  float* agg1 = (float*)allocB((size_t)N * F * 4);  // reused as h2
  float* z1 = (float*)allocB((size_t)N * HID * 4);
  unsigned short* w1th = (unsigned short*)allocB((size_t)F * HID * 2);
  unsigned short* w1tl = (unsigned short*)allocB((size_t)F * HID * 2);
  unsigned short* w2th = (unsigned short*)allocB((size_t)HID * F * 2);
  unsigned short* w2tl = (unsigned short*)allocB((size_t)HID * F * 2);
  float* h2 = agg1;

  int nbN = (N + 255) / 256;
  int nbE = (E + 255) / 256;
  int nbW = (F * HID + 255) / 256;

  k_wsplit<<<nbW, 256, 0, stream>>>(W1, w1th, w1tl, F, HID);    // [HID][F]
  k_wsplit<<<nbW, 256, 0, stream>>>(W2, w2th, w2tl, HID, F);    // [F][HID]

  k_zero_deg<<<nbN, 256, 0, stream>>>(deg, N);
  k_deg_hist<<<nbE, 256, 0, stream>>>(dst, deg, E);
  k_dinv<<<nbN, 256, 0, stream>>>(deg, dinv, N);
  k_scan1<<<nbN, 256, 0, stream>>>(deg, rowptr, bsum, N);
  k_scan2<<<1, 256, 0, stream>>>(bsum, rowptr, nbN, N);
  k_scan3<<<nbN, 256, 0, stream>>>(bsum, rowptr, deg, N);
  k_scatter<<<nbE, 256, 0, stream>>>(src, dst, rowptr, deg, dinv, esrc, ew, E);

  int nbAgg = (N + 3) / 4;
  int mb = (N + 63) / 64;

  // layer 1: agg1 = A x ; z1 = relu(agg1 @ W1 + b1)
  k_agg<0><<<nbAgg, 256, 0, stream>>>(rowptr, esrc, ew, dinv, x, nullptr, agg1, N);
  dim3 g1(mb, HID / 64);
  k_mgemm<<<g1, 256, 0, stream>>>(agg1, w1th, w1tl, b1, z1, N, F, HID, 1);

  // layer 2: h2 = z1 @ W2 ; out = b2 + A h2
  dim3 g2(mb, F / 64);
  k_mgemm<<<g2, 256, 0, stream>>>(z1, w2th, w2tl, nullptr, h2, N, HID, F, 0);
  k_agg<1><<<nbAgg, 256, 0, stream>>>(rowptr, esrc, ew, dinv, h2, b2, out, N);
}